// Round 2
// baseline (2191.090 us; speedup 1.0000x reference)
//
#include <hip/hip_runtime.h>
#include <math.h>

#define CHUNK 4

// ---------------------------------------------------------------------------
// Generic tiled direct conv: 16x16 spatial tile per block, OCB output
// channels per block, input channels staged through LDS in chunks of CHUNK.
// ACT: 0=none 1=relu 2=tanh 3=sigmoid
// ---------------------------------------------------------------------------
template<int K, int ACT, int OCB>
__global__ __launch_bounds__(256)
void conv2d_kernel(const float* __restrict__ in, const float* __restrict__ w,
                   const float* __restrict__ bias, float* __restrict__ out,
                   int B, int Cin, int H, int Wd, int Cout)
{
    constexpr int PAD = K / 2;
    constexpr int T = 16 + K - 1;
    constexpr int KK = K * K;
    __shared__ float tile[CHUNK][T][T + 1];

    const int tx = threadIdx.x, ty = threadIdx.y;
    const int tid = ty * 16 + tx;
    const int tilesX = (Wd + 15) >> 4;
    const int bx = blockIdx.x % tilesX, by = blockIdx.x / tilesX;
    const int x0 = bx * 16, y0 = by * 16;
    const int ox = x0 + tx, oy = y0 + ty;
    const int oc0 = blockIdx.y * OCB;
    const int b = blockIdx.z;

    int wb[OCB];
#pragma unroll
    for (int o = 0; o < OCB; ++o) {
        int oc = oc0 + o;
        if (oc > Cout - 1) oc = Cout - 1;   // clamp to stay in-bounds
        wb[o] = oc * Cin * KK;
    }

    float acc[OCB];
#pragma unroll
    for (int o = 0; o < OCB; ++o) acc[o] = 0.f;

    for (int c0 = 0; c0 < Cin; c0 += CHUNK) {
        int nc = Cin - c0;
        if (nc > CHUNK) nc = CHUNK;
        __syncthreads();
        for (int i = tid; i < nc * T * T; i += 256) {
            int cc = i / (T * T);
            int r = i - cc * T * T;
            int yy = r / T, xx = r - yy * T;
            int iy = y0 + yy - PAD, ix = x0 + xx - PAD;
            float v = 0.f;
            if (iy >= 0 && iy < H && ix >= 0 && ix < Wd)
                v = in[((b * Cin + c0 + cc) * H + iy) * Wd + ix];
            tile[cc][yy][xx] = v;
        }
        __syncthreads();
        for (int cc = 0; cc < nc; ++cc) {
            const float* wp = w + (c0 + cc) * KK;
#pragma unroll
            for (int ky = 0; ky < K; ++ky) {
#pragma unroll
                for (int kx = 0; kx < K; ++kx) {
                    float v = tile[cc][ty + ky][tx + kx];
#pragma unroll
                    for (int o = 0; o < OCB; ++o)
                        acc[o] = fmaf(v, wp[wb[o] + ky * K + kx], acc[o]);
                }
            }
        }
    }

    if (ox < Wd && oy < H) {
#pragma unroll
        for (int o = 0; o < OCB; ++o) {
            int oc = oc0 + o;
            if (oc < Cout) {
                float r = acc[o] + bias[oc];
                if (ACT == 1) r = fmaxf(r, 0.f);
                if (ACT == 2) r = tanhf(r);
                if (ACT == 3) r = 1.f / (1.f + __expf(-r));
                out[((b * Cout + oc) * H + oy) * Wd + ox] = r;
            }
        }
    }
}

template<int K, int ACT>
static inline void conv_launch(const float* in, const float* w, const float* b, float* o,
                               int B, int Cin, int H, int W, int Cout, hipStream_t s)
{
    dim3 blk(16, 16, 1);
    int tcx = (W + 15) / 16, tcy = (H + 15) / 16;
    dim3 grd(tcx * tcy, (Cout + 7) / 8, B);
    hipLaunchKernelGGL((conv2d_kernel<K, ACT, 8>), grd, blk, 0, s,
                       in, w, b, o, B, Cin, H, W, Cout);
}

// ---------------------------------------------------------------------------
// 2x2 max pool, stride 2
// ---------------------------------------------------------------------------
__global__ void maxpool2_kernel(const float* __restrict__ in, float* __restrict__ out,
                                int total, int Ho, int Wo)
{
    int idx = blockIdx.x * 256 + threadIdx.x;
    if (idx >= total) return;
    int x = idx % Wo;
    int t = idx / Wo;
    int y = t % Ho;
    int bc = t / Ho;
    int Wi = Wo * 2;
    const float* p = in + ((bc * 2 * Ho + 2 * y) * Wi + 2 * x);
    out[idx] = fmaxf(fmaxf(p[0], p[1]), fmaxf(p[Wi], p[Wi + 1]));
}

// ---------------------------------------------------------------------------
// Fused 2x bilinear upsample (half-pixel centers, edge clamp) + channel concat
// dst[B, C1+C2, H, W] = cat(upsample(up[B,C1,H/2,W/2]), skip[B,C2,H,W])
// (jax.image.resize bilinear at exact 2x: boundary renormalization == clamp)
// ---------------------------------------------------------------------------
__global__ void upcat_kernel(const float* __restrict__ up, const float* __restrict__ skip,
                             float* __restrict__ dst, int B, int C1, int C2, int H, int W)
{
    int total = B * (C1 + C2) * H * W;
    int idx = blockIdx.x * 256 + threadIdx.x;
    if (idx >= total) return;
    int x = idx % W;
    int t = idx / W;
    int y = t % H;
    t /= H;
    int c = t % (C1 + C2);
    int b = t / (C1 + C2);
    float r;
    if (c < C1) {
        int Hi = H >> 1, Wi = W >> 1;
        float fy = 0.5f * y - 0.25f;
        float fx = 0.5f * x - 0.25f;
        float y0f = floorf(fy), x0f = floorf(fx);
        float wy = fy - y0f, wx = fx - x0f;
        int yA = (int)y0f, xA = (int)x0f;
        int yB = yA + 1, xB = xA + 1;
        yA = yA < 0 ? 0 : (yA > Hi - 1 ? Hi - 1 : yA);
        yB = yB < 0 ? 0 : (yB > Hi - 1 ? Hi - 1 : yB);
        xA = xA < 0 ? 0 : (xA > Wi - 1 ? Wi - 1 : xA);
        xB = xB < 0 ? 0 : (xB > Wi - 1 ? Wi - 1 : xB);
        const float* sp = up + ((b * C1 + c) * Hi) * Wi;
        float v00 = sp[yA * Wi + xA], v01 = sp[yA * Wi + xB];
        float v10 = sp[yB * Wi + xA], v11 = sp[yB * Wi + xB];
        r = (1.f - wy) * ((1.f - wx) * v00 + wx * v01) +
            wy * ((1.f - wx) * v10 + wx * v11);
    } else {
        r = skip[((b * C2 + (c - C1)) * H + y) * W + x];
    }
    dst[idx] = r;
}

// ---------------------------------------------------------------------------
// LRNN scans.  h = (1-p)*x + p*h_prev = fma(p, h_prev - x, x), h0 = 0.
// Reverse directions: reference flips X,P, scans, and does NOT unflip ->
// output index i holds the state after consuming original index L-1-i.
// W-scans use fm channel offsets {0, 32}; H-scans use {16, 48}.
// out is max-accumulated in place (W-fwd initializes).
// ---------------------------------------------------------------------------
__global__ void lrnn_w_kernel(const float* __restrict__ X, const float* __restrict__ FM,
                              float* __restrict__ out, int B, int H, int W,
                              int rev, int init)
{
    int total = B * 16 * H;
    int idx = blockIdx.x * 256 + threadIdx.x;
    if (idx >= total) return;
    int y = idx % H;
    int c = (idx / H) & 15;
    int b = idx / (H * 16);
    const float4* xr  = (const float4*)(X  + (size_t)((b * 16 + c) * H + y) * W);
    const float4* p1r = (const float4*)(FM + (size_t)((b * 64 + c) * H + y) * W);
    const float4* p2r = (const float4*)(FM + (size_t)((b * 64 + 32 + c) * H + y) * W);
    float4* orow = (float4*)(out + (size_t)((b * 16 + c) * H + y) * W);
    int nv = W >> 2;
    float h1 = 0.f, h2 = 0.f;
    for (int v = 0; v < nv; ++v) {
        int rb = rev ? (nv - 1 - v) : v;
        float4 xv = xr[rb], pa = p1r[rb], pb = p2r[rb];
        float4 m;
        if (!rev) {
            h1 = fmaf(pa.x, h1 - xv.x, xv.x); h2 = fmaf(pb.x, h2 - xv.x, xv.x); m.x = fmaxf(h1, h2);
            h1 = fmaf(pa.y, h1 - xv.y, xv.y); h2 = fmaf(pb.y, h2 - xv.y, xv.y); m.y = fmaxf(h1, h2);
            h1 = fmaf(pa.z, h1 - xv.z, xv.z); h2 = fmaf(pb.z, h2 - xv.z, xv.z); m.z = fmaxf(h1, h2);
            h1 = fmaf(pa.w, h1 - xv.w, xv.w); h2 = fmaf(pb.w, h2 - xv.w, xv.w); m.w = fmaxf(h1, h2);
        } else {
            // consume .w,.z,.y,.x ; store in step order
            h1 = fmaf(pa.w, h1 - xv.w, xv.w); h2 = fmaf(pb.w, h2 - xv.w, xv.w); m.x = fmaxf(h1, h2);
            h1 = fmaf(pa.z, h1 - xv.z, xv.z); h2 = fmaf(pb.z, h2 - xv.z, xv.z); m.y = fmaxf(h1, h2);
            h1 = fmaf(pa.y, h1 - xv.y, xv.y); h2 = fmaf(pb.y, h2 - xv.y, xv.y); m.z = fmaxf(h1, h2);
            h1 = fmaf(pa.x, h1 - xv.x, xv.x); h2 = fmaf(pb.x, h2 - xv.x, xv.x); m.w = fmaxf(h1, h2);
        }
        if (!init) {
            float4 o = orow[v];
            m.x = fmaxf(m.x, o.x); m.y = fmaxf(m.y, o.y);
            m.z = fmaxf(m.z, o.z); m.w = fmaxf(m.w, o.w);
        }
        orow[v] = m;
    }
}

__global__ void lrnn_h_kernel(const float* __restrict__ X, const float* __restrict__ FM,
                              float* __restrict__ out, int B, int H, int W, int rev)
{
    int total = B * 16 * W;
    int idx = blockIdx.x * 256 + threadIdx.x;
    if (idx >= total) return;
    int x = idx % W;
    int c = (idx / W) & 15;
    int b = idx / (W * 16);
    const float* xc  = X  + (size_t)((b * 16 + c) * H) * W + x;
    const float* p1c = FM + (size_t)((b * 64 + 16 + c) * H) * W + x;
    const float* p2c = FM + (size_t)((b * 64 + 48 + c) * H) * W + x;
    float* ocp = out + (size_t)((b * 16 + c) * H) * W + x;
    float h1 = 0.f, h2 = 0.f;
    for (int i = 0; i < H; ++i) {
        int yr = rev ? (H - 1 - i) : i;
        float xv = xc[yr * W];
        float p1 = p1c[yr * W], p2 = p2c[yr * W];
        h1 = fmaf(p1, h1 - xv, xv);
        h2 = fmaf(p2, h2 - xv, xv);
        float m = fmaxf(h1, h2);
        ocp[i * W] = fmaxf(ocp[i * W], m);
    }
}

// ---------------------------------------------------------------------------
extern "C" void kernel_launch(void* const* d_in, const int* in_sizes, int n_in,
                              void* d_out, int out_size, void* d_ws, size_t ws_size,
                              hipStream_t stream)
{
    const float* img = (const float*)d_in[0];
    const float* w1 = (const float*)d_in[1];  const float* b1 = (const float*)d_in[2];
    const float* w2 = (const float*)d_in[3];  const float* b2 = (const float*)d_in[4];
    const float* w3 = (const float*)d_in[5];  const float* b3 = (const float*)d_in[6];
    const float* w4 = (const float*)d_in[7];  const float* b4 = (const float*)d_in[8];
    const float* w5 = (const float*)d_in[9];  const float* b5 = (const float*)d_in[10];
    const float* w6 = (const float*)d_in[11]; const float* b6 = (const float*)d_in[12];
    const float* w7 = (const float*)d_in[13]; const float* b7 = (const float*)d_in[14];
    const float* w8 = (const float*)d_in[15]; const float* b8 = (const float*)d_in[16];
    const float* w9 = (const float*)d_in[17]; const float* b9 = (const float*)d_in[18];
    const float* wi = (const float*)d_in[19]; const float* bi = (const float*)d_in[20];
    const float* wo = (const float*)d_in[21]; const float* bo = (const float*)d_in[22];

    float* ws = (float*)d_ws;
    const size_t MBf = (size_t)(1u << 20) / 4;  // floats per MiB
    // Bump allocation with reuse; peak = 228 MiB.
    // (R1 fix: cat8 is 32 MiB, not 16 -- x8 used to overlap its second half.)
    float* x1   = ws;                 // [0,32)    [8,16,256,256]
    float* p1   = ws + 32 * MBf;      // [32,40)   [8,16,128,128]
    float* x2   = ws + 40 * MBf;      // [40,56)   [8,32,128,128]
    float* p2   = ws + 56 * MBf;      // [56,60)   [8,32,64,64]
    float* x3   = ws + 60 * MBf;      // [60,64)   [8,32,64,64]
    float* p3   = ws + 64 * MBf;      // [64,65)   [8,32,32,32]
    float* x4   = ws + 65 * MBf;      // [65,66)   [8,32,32,32]
    float* p4   = ws + 66 * MBf;      // [66,67)   [8,32,16,16]
    float* x5   = ws + 67 * MBf;      // [67,68)   [8,64,16,16]
    float* cat6 = ws + 68 * MBf;      // [68,71)   [8,96,32,32]
    float* x6   = ws + 71 * MBf;      // [71,72)   [8,32,32,32]
    float* cat7 = ws + 72 * MBf;      // [72,80)   [8,64,64,64]
    float* x7   = ws + 80 * MBf;      // [80,84)   [8,32,64,64]
    float* cat8 = ws + 84 * MBf;      // [84,116)  [8,64,128,128]  32 MiB
    float* x8   = ws + 116 * MBf;     // [116,132) [8,32,128,128]  16 MiB
    float* cat9 = ws + 132 * MBf;     // [132,228) [8,48,256,256]  96 MiB
    float* fm   = ws;                 // [0,128)   [8,64,256,256]  (x1..x8 dead)
    float* xin  = ws + 132 * MBf;     // [132,164) reuses cat9 (dead after fm conv)
    float* rnn  = ws + 164 * MBf;     // [164,196)
    float* outp = (float*)d_out;

    const int B = 8;

    // --- encoder ---
    conv_launch<5, 1>(img, w1, b1, x1, B, 15, 256, 256, 16, stream);
    { int tot = B * 16 * 128 * 128;
      maxpool2_kernel<<<(tot + 255) / 256, 256, 0, stream>>>(x1, p1, tot, 128, 128); }
    conv_launch<3, 1>(p1, w2, b2, x2, B, 16, 128, 128, 32, stream);
    { int tot = B * 32 * 64 * 64;
      maxpool2_kernel<<<(tot + 255) / 256, 256, 0, stream>>>(x2, p2, tot, 64, 64); }
    conv_launch<3, 1>(p2, w3, b3, x3, B, 32, 64, 64, 32, stream);
    { int tot = B * 32 * 32 * 32;
      maxpool2_kernel<<<(tot + 255) / 256, 256, 0, stream>>>(x3, p3, tot, 32, 32); }
    conv_launch<3, 1>(p3, w4, b4, x4, B, 32, 32, 32, 32, stream);
    { int tot = B * 32 * 16 * 16;
      maxpool2_kernel<<<(tot + 255) / 256, 256, 0, stream>>>(x4, p4, tot, 16, 16); }
    conv_launch<3, 1>(p4, w5, b5, x5, B, 32, 16, 16, 64, stream);

    // --- decoder ---
    { int tot = B * 96 * 32 * 32;
      upcat_kernel<<<(tot + 255) / 256, 256, 0, stream>>>(x5, x4, cat6, B, 64, 32, 32, 32); }
    conv_launch<3, 1>(cat6, w6, b6, x6, B, 96, 32, 32, 32, stream);
    { int tot = B * 64 * 64 * 64;
      upcat_kernel<<<(tot + 255) / 256, 256, 0, stream>>>(x6, x3, cat7, B, 32, 32, 64, 64); }
    conv_launch<3, 1>(cat7, w7, b7, x7, B, 64, 64, 64, 32, stream);
    { int tot = B * 64 * 128 * 128;
      upcat_kernel<<<(tot + 255) / 256, 256, 0, stream>>>(x7, x2, cat8, B, 32, 32, 128, 128); }
    conv_launch<3, 1>(cat8, w8, b8, x8, B, 64, 128, 128, 32, stream);
    { int tot = B * 48 * 256 * 256;
      upcat_kernel<<<(tot + 255) / 256, 256, 0, stream>>>(x8, x1, cat9, B, 32, 16, 256, 256); }
    conv_launch<3, 2>(cat9, w9, b9, fm, B, 48, 256, 256, 64, stream);  // tanh -> fm

    // --- input projection ---
    conv_launch<3, 0>(img, wi, bi, xin, B, 15, 256, 256, 16, stream);

    // --- spatial RNN: 8 directions, max-combined in place ---
    { int tot = B * 16 * 256; int g = (tot + 255) / 256;
      lrnn_w_kernel<<<g, 256, 0, stream>>>(xin, fm, rnn, B, 256, 256, 0, 1);
      lrnn_w_kernel<<<g, 256, 0, stream>>>(xin, fm, rnn, B, 256, 256, 1, 0);
      lrnn_h_kernel<<<g, 256, 0, stream>>>(xin, fm, rnn, B, 256, 256, 0);
      lrnn_h_kernel<<<g, 256, 0, stream>>>(xin, fm, rnn, B, 256, 256, 1); }

    // --- output head ---
    conv_launch<3, 3>(rnn, wo, bo, outp, B, 16, 256, 256, 3, stream);
}